// Round 1
// baseline (43.067 us; speedup 1.0000x reference)
//
#include <hip/hip_runtime.h>

// Batched GEMM formulation of AbsolutePosEmb:
//   per batch b,n (32 of them):
//     C[xy][pq] = sum_d Q[xy][d] * (K[pq][d] + ph[p][d] + pw[q][d])
//   M = N = 1024 (HW), K = 64 (D). Output f32, compute bf16 MFMA (f32 accum).
//
// Memory-bound by the 128 MiB output write. 128x128 tiles, 4 waves/block,
// each wave 64x64 via mfma_f32_32x32x16_bf16. LDS row stride padded to 72
// bf16 (144 B) for conflict-free ds_read_b128.

typedef __bf16 bf16x8 __attribute__((ext_vector_type(8)));
typedef __bf16 bf16x4 __attribute__((ext_vector_type(4)));
typedef float  f32x16 __attribute__((ext_vector_type(16)));

#define LDSTRIDE 72   // bf16 elements per LDS row (64 data + 8 pad)

__global__ __launch_bounds__(256)
void abs_pos_emb_gemm(const float* __restrict__ q,
                      const float* __restrict__ k,
                      const float* __restrict__ ph,
                      const float* __restrict__ pw,
                      float* __restrict__ out)
{
    __shared__ __bf16 As[128 * LDSTRIDE];   // Q tile   (128 rows x 64 d)
    __shared__ __bf16 Bs[128 * LDSTRIDE];   // K+emb tile

    const int tid   = threadIdx.x;
    const int bid   = blockIdx.x;
    const int batch = bid >> 6;            // 32 batches (B*N)
    const int tile  = bid & 63;            // 8x8 tiles of 128x128
    const int trow  = (tile >> 3) << 7;    // tile row base in [0,1024)
    const int tcol  = (tile & 7)  << 7;    // tile col base (pq)

    const float* Qb = q + (size_t)batch * (1024 * 64);
    const float* Kb = k + (size_t)batch * (1024 * 64);

    // ---- stage A: Q tile -> bf16 LDS (coalesced float4 loads) ----
#pragma unroll
    for (int i = 0; i < 8; ++i) {
        int f   = i * 256 + tid;          // float4 index within 128x64 tile
        int row = f >> 4;                 // 16 float4 per row
        int col = (f & 15) << 2;
        float4 v = *reinterpret_cast<const float4*>(
            Qb + (size_t)(trow + row) * 64 + col);
        bf16x4 h;
        h[0] = (__bf16)v.x; h[1] = (__bf16)v.y;
        h[2] = (__bf16)v.z; h[3] = (__bf16)v.w;
        *reinterpret_cast<bf16x4*>(&As[row * LDSTRIDE + col]) = h;
    }

    // ---- stage B: (K + ph[p] + pw[q]) tile -> bf16 LDS ----
#pragma unroll
    for (int i = 0; i < 8; ++i) {
        int f   = i * 256 + tid;
        int row = f >> 4;
        int col = (f & 15) << 2;
        int grow = tcol + row;            // pq row index in [0,1024)
        int p  = grow >> 5;               // H index
        int qq = grow & 31;               // W index
        float4 v  = *reinterpret_cast<const float4*>(
            Kb + (size_t)grow * 64 + col);
        float4 vp = *reinterpret_cast<const float4*>(ph + p  * 64 + col);
        float4 vw = *reinterpret_cast<const float4*>(pw + qq * 64 + col);
        bf16x4 h;
        h[0] = (__bf16)(v.x + vp.x + vw.x);
        h[1] = (__bf16)(v.y + vp.y + vw.y);
        h[2] = (__bf16)(v.z + vp.z + vw.z);
        h[3] = (__bf16)(v.w + vp.w + vw.w);
        *reinterpret_cast<bf16x4*>(&Bs[row * LDSTRIDE + col]) = h;
    }

    __syncthreads();

    // ---- MFMA compute: each wave owns a 64x64 output sub-tile ----
    const int lane = tid & 63;
    const int wid  = tid >> 6;
    const int wr   = (wid >> 1) << 6;     // wave row base within tile
    const int wc   = (wid & 1)  << 6;     // wave col base within tile
    const int fr   = lane & 31;           // fragment row/col
    const int fk   = (lane >> 5) << 3;    // k sub-offset (0 or 8)

    f32x16 acc[2][2] = {};

#pragma unroll
    for (int kk = 0; kk < 4; ++kk) {      // K = 64 = 4 steps of 16
        const int kb = kk * 16 + fk;      // bf16 element offset in row
        bf16x8 a0 = *reinterpret_cast<const bf16x8*>(&As[(wr      + fr) * LDSTRIDE + kb]);
        bf16x8 a1 = *reinterpret_cast<const bf16x8*>(&As[(wr + 32 + fr) * LDSTRIDE + kb]);
        bf16x8 b0 = *reinterpret_cast<const bf16x8*>(&Bs[(wc      + fr) * LDSTRIDE + kb]);
        bf16x8 b1 = *reinterpret_cast<const bf16x8*>(&Bs[(wc + 32 + fr) * LDSTRIDE + kb]);
        acc[0][0] = __builtin_amdgcn_mfma_f32_32x32x16_bf16(a0, b0, acc[0][0], 0, 0, 0);
        acc[0][1] = __builtin_amdgcn_mfma_f32_32x32x16_bf16(a0, b1, acc[0][1], 0, 0, 0);
        acc[1][0] = __builtin_amdgcn_mfma_f32_32x32x16_bf16(a1, b0, acc[1][0], 0, 0, 0);
        acc[1][1] = __builtin_amdgcn_mfma_f32_32x32x16_bf16(a1, b1, acc[1][1], 0, 0, 0);
    }

    // ---- store: C/D layout col=lane&31, row=(reg&3)+8*(reg>>2)+4*(lane>>5) ----
    float* Ob = out + (size_t)batch * (1024u * 1024u);
    const int srow = trow + wr + ((lane >> 5) << 2);
    const int scol = tcol + wc + (lane & 31);

#pragma unroll
    for (int m = 0; m < 2; ++m) {
#pragma unroll
        for (int n = 0; n < 2; ++n) {
            float* po = Ob + (size_t)(srow + m * 32) * 1024 + (scol + n * 32);
#pragma unroll
            for (int r = 0; r < 16; ++r) {
                int roff = (r & 3) + ((r >> 2) << 3);
                po[(size_t)roff * 1024] = acc[m][n][r];
            }
        }
    }
}

extern "C" void kernel_launch(void* const* d_in, const int* in_sizes, int n_in,
                              void* d_out, int out_size, void* d_ws, size_t ws_size,
                              hipStream_t stream) {
    const float* q  = (const float*)d_in[0];
    const float* k  = (const float*)d_in[1];
    const float* ph = (const float*)d_in[2];
    const float* pw = (const float*)d_in[3];
    float* out = (float*)d_out;

    // 32 batches * 64 tiles (8x8 of 128x128) = 2048 blocks, 256 threads each
    hipLaunchKernelGGL(abs_pos_emb_gemm, dim3(2048), dim3(256), 0, stream,
                       q, k, ph, pw, out);
}

// Round 2
// 34.355 us; speedup vs baseline: 1.2536x; 1.2536x over previous
//
#include <hip/hip_runtime.h>

// Batched GEMM formulation of AbsolutePosEmb:
//   per batch b,n (32 of them):
//     C[xy][pq] = sum_d Q[xy][d] * (K[pq][d] + ph[p][d] + pw[q][d])
//   M = N = 1024 (HW), K = 64 (D). Output f32, compute bf16 MFMA (f32 accum).
//
// Memory-bound by the 128 MiB output write. 128x128 tiles, 4 waves/block,
// each wave 64x64 via mfma_f32_32x32x16_bf16. LDS row stride padded to 72
// bf16 (144 B).
//
// Round-1 locality fixes:
//  - batch = bid & 31  => all 64 tiles of a batch land on ONE XCD
//    (bid mod 8 == batch mod 8 since 32 % 8 == 0): Q/K re-reads (8x each)
//    become local-L2 hits instead of cross-XCD L3/HBM traffic.
//  - nontemporal output stores: 16.8 MB/XCD of write stream must not evict
//    the 2 MiB/XCD resident Q/K working set from L2.

typedef __bf16 bf16x8 __attribute__((ext_vector_type(8)));
typedef __bf16 bf16x4 __attribute__((ext_vector_type(4)));
typedef float  f32x16 __attribute__((ext_vector_type(16)));

#define LDSTRIDE 72   // bf16 elements per LDS row (64 data + 8 pad)

__global__ __launch_bounds__(256)
void abs_pos_emb_gemm(const float* __restrict__ q,
                      const float* __restrict__ k,
                      const float* __restrict__ ph,
                      const float* __restrict__ pw,
                      float* __restrict__ out)
{
    __shared__ __bf16 As[128 * LDSTRIDE];   // Q tile   (128 rows x 64 d)
    __shared__ __bf16 Bs[128 * LDSTRIDE];   // K+emb tile

    const int tid   = threadIdx.x;
    const int bid   = blockIdx.x;
    const int batch = bid & 31;            // batch mod 8 == XCD -> L2 locality
    const int tile  = bid >> 5;            // 8x8 tiles of 128x128
    const int trow  = (tile >> 3) << 7;    // tile row base in [0,1024)
    const int tcol  = (tile & 7)  << 7;    // tile col base (pq)

    const float* Qb = q + (size_t)batch * (1024 * 64);
    const float* Kb = k + (size_t)batch * (1024 * 64);

    // ---- stage A: Q tile -> bf16 LDS (coalesced float4 loads) ----
#pragma unroll
    for (int i = 0; i < 8; ++i) {
        int f   = i * 256 + tid;          // float4 index within 128x64 tile
        int row = f >> 4;                 // 16 float4 per row
        int col = (f & 15) << 2;
        float4 v = *reinterpret_cast<const float4*>(
            Qb + (size_t)(trow + row) * 64 + col);
        bf16x4 h;
        h[0] = (__bf16)v.x; h[1] = (__bf16)v.y;
        h[2] = (__bf16)v.z; h[3] = (__bf16)v.w;
        *reinterpret_cast<bf16x4*>(&As[row * LDSTRIDE + col]) = h;
    }

    // ---- stage B: (K + ph[p] + pw[q]) tile -> bf16 LDS ----
#pragma unroll
    for (int i = 0; i < 8; ++i) {
        int f   = i * 256 + tid;
        int row = f >> 4;
        int col = (f & 15) << 2;
        int grow = tcol + row;            // pq row index in [0,1024)
        int p  = grow >> 5;               // H index
        int qq = grow & 31;               // W index
        float4 v  = *reinterpret_cast<const float4*>(
            Kb + (size_t)grow * 64 + col);
        float4 vp = *reinterpret_cast<const float4*>(ph + p  * 64 + col);
        float4 vw = *reinterpret_cast<const float4*>(pw + qq * 64 + col);
        bf16x4 h;
        h[0] = (__bf16)(v.x + vp.x + vw.x);
        h[1] = (__bf16)(v.y + vp.y + vw.y);
        h[2] = (__bf16)(v.z + vp.z + vw.z);
        h[3] = (__bf16)(v.w + vp.w + vw.w);
        *reinterpret_cast<bf16x4*>(&Bs[row * LDSTRIDE + col]) = h;
    }

    __syncthreads();

    // ---- MFMA compute: each wave owns a 64x64 output sub-tile ----
    const int lane = tid & 63;
    const int wid  = tid >> 6;
    const int wr   = (wid >> 1) << 6;     // wave row base within tile
    const int wc   = (wid & 1)  << 6;     // wave col base within tile
    const int fr   = lane & 31;           // fragment row/col
    const int fk   = (lane >> 5) << 3;    // k sub-offset (0 or 8)

    f32x16 acc[2][2] = {};

#pragma unroll
    for (int kk = 0; kk < 4; ++kk) {      // K = 64 = 4 steps of 16
        const int kb = kk * 16 + fk;      // bf16 element offset in row
        bf16x8 a0 = *reinterpret_cast<const bf16x8*>(&As[(wr      + fr) * LDSTRIDE + kb]);
        bf16x8 a1 = *reinterpret_cast<const bf16x8*>(&As[(wr + 32 + fr) * LDSTRIDE + kb]);
        bf16x8 b0 = *reinterpret_cast<const bf16x8*>(&Bs[(wc      + fr) * LDSTRIDE + kb]);
        bf16x8 b1 = *reinterpret_cast<const bf16x8*>(&Bs[(wc + 32 + fr) * LDSTRIDE + kb]);
        acc[0][0] = __builtin_amdgcn_mfma_f32_32x32x16_bf16(a0, b0, acc[0][0], 0, 0, 0);
        acc[0][1] = __builtin_amdgcn_mfma_f32_32x32x16_bf16(a0, b1, acc[0][1], 0, 0, 0);
        acc[1][0] = __builtin_amdgcn_mfma_f32_32x32x16_bf16(a1, b0, acc[1][0], 0, 0, 0);
        acc[1][1] = __builtin_amdgcn_mfma_f32_32x32x16_bf16(a1, b1, acc[1][1], 0, 0, 0);
    }

    // ---- store: C/D layout col=lane&31, row=(reg&3)+8*(reg>>2)+4*(lane>>5) ----
    float* Ob = out + (size_t)batch * (1024u * 1024u);
    const int srow = trow + wr + ((lane >> 5) << 2);
    const int scol = tcol + wc + (lane & 31);

#pragma unroll
    for (int m = 0; m < 2; ++m) {
#pragma unroll
        for (int n = 0; n < 2; ++n) {
            float* po = Ob + (size_t)(srow + m * 32) * 1024 + (scol + n * 32);
#pragma unroll
            for (int r = 0; r < 16; ++r) {
                int roff = (r & 3) + ((r >> 2) << 3);
                __builtin_nontemporal_store(acc[m][n][r], po + (size_t)roff * 1024);
            }
        }
    }
}

extern "C" void kernel_launch(void* const* d_in, const int* in_sizes, int n_in,
                              void* d_out, int out_size, void* d_ws, size_t ws_size,
                              hipStream_t stream) {
    const float* q  = (const float*)d_in[0];
    const float* k  = (const float*)d_in[1];
    const float* ph = (const float*)d_in[2];
    const float* pw = (const float*)d_in[3];
    float* out = (float*)d_out;

    // 32 batches * 64 tiles (8x8 of 128x128) = 2048 blocks, 256 threads each
    hipLaunchKernelGGL(abs_pos_emb_gemm, dim3(2048), dim3(256), 0, stream,
                       q, k, ph, pw, out);
}

// Round 3
// 33.203 us; speedup vs baseline: 1.2971x; 1.0347x over previous
//
#include <hip/hip_runtime.h>

// Batched GEMM formulation of AbsolutePosEmb:
//   per batch b,n (32 of them):
//     C[xy][pq] = sum_d Q[xy][d] * (K[pq][d] + ph[p][d] + pw[q][d])
//   M = N = 1024 (HW), K = 64 (D). Output f32, compute bf16 MFMA (f32 accum).
//
// Memory-bound by the 128 MiB output write (pure-write ceiling measured at
// ~6.85 TB/s via harness fill kernels -> ~22 us floor incl. 17 MB reads).
//
// Locality scheme (round 2):
//  - CHUNKED batch->XCD mapping: blocks dispatch round-robin to XCDs by
//    bid%8. We map per-XCD ordinal n=bid>>3 so each XCD runs its 4 batches
//    SEQUENTIALLY (batch = (bid&7)*4 + (bid>>9), tile = n&63). Instantaneous
//    read working set per XCD = one batch's Q+K = 512 KB << 4 MB L2, even
//    under the streaming-write pressure. (Round-1's interleaved mapping kept
//    4 batches = 2 MB hot simultaneously -> suspected L2 thrash to L3.)
//  - nontemporal output stores: write stream must not evict Q/K from L2.

typedef __bf16 bf16x8 __attribute__((ext_vector_type(8)));
typedef __bf16 bf16x4 __attribute__((ext_vector_type(4)));
typedef float  f32x16 __attribute__((ext_vector_type(16)));

#define LDSTRIDE 72   // bf16 elements per LDS row (64 data + 8 pad)

__global__ __launch_bounds__(256)
void abs_pos_emb_gemm(const float* __restrict__ q,
                      const float* __restrict__ k,
                      const float* __restrict__ ph,
                      const float* __restrict__ pw,
                      float* __restrict__ out)
{
    __shared__ __bf16 As[128 * LDSTRIDE];   // Q tile   (128 rows x 64 d)
    __shared__ __bf16 Bs[128 * LDSTRIDE];   // K+emb tile

    const int tid   = threadIdx.x;
    const int bid   = blockIdx.x;
    // chunked XCD mapping: XCD x = bid&7 runs batches x*4 .. x*4+3 in order
    const int batch = ((bid & 7) << 2) + (bid >> 9);
    const int tile  = (bid >> 3) & 63;     // 8x8 tiles of 128x128, row-major
    const int trow  = (tile >> 3) << 7;    // tile row base in [0,1024)
    const int tcol  = (tile & 7)  << 7;    // tile col base (pq)

    const float* Qb = q + (size_t)batch * (1024 * 64);
    const float* Kb = k + (size_t)batch * (1024 * 64);

    // ---- stage A: Q tile -> bf16 LDS (coalesced float4 loads) ----
#pragma unroll
    for (int i = 0; i < 8; ++i) {
        int f   = i * 256 + tid;          // float4 index within 128x64 tile
        int row = f >> 4;                 // 16 float4 per row
        int col = (f & 15) << 2;
        float4 v = *reinterpret_cast<const float4*>(
            Qb + (size_t)(trow + row) * 64 + col);
        bf16x4 h;
        h[0] = (__bf16)v.x; h[1] = (__bf16)v.y;
        h[2] = (__bf16)v.z; h[3] = (__bf16)v.w;
        *reinterpret_cast<bf16x4*>(&As[row * LDSTRIDE + col]) = h;
    }

    // ---- stage B: (K + ph[p] + pw[q]) tile -> bf16 LDS ----
#pragma unroll
    for (int i = 0; i < 8; ++i) {
        int f   = i * 256 + tid;
        int row = f >> 4;
        int col = (f & 15) << 2;
        int grow = tcol + row;            // pq row index in [0,1024)
        int p  = grow >> 5;               // H index
        int qq = grow & 31;               // W index
        float4 v  = *reinterpret_cast<const float4*>(
            Kb + (size_t)grow * 64 + col);
        float4 vp = *reinterpret_cast<const float4*>(ph + p  * 64 + col);
        float4 vw = *reinterpret_cast<const float4*>(pw + qq * 64 + col);
        bf16x4 h;
        h[0] = (__bf16)(v.x + vp.x + vw.x);
        h[1] = (__bf16)(v.y + vp.y + vw.y);
        h[2] = (__bf16)(v.z + vp.z + vw.z);
        h[3] = (__bf16)(v.w + vp.w + vw.w);
        *reinterpret_cast<bf16x4*>(&Bs[row * LDSTRIDE + col]) = h;
    }

    __syncthreads();

    // ---- MFMA compute: each wave owns a 64x64 output sub-tile ----
    const int lane = tid & 63;
    const int wid  = tid >> 6;
    const int wr   = (wid >> 1) << 6;     // wave row base within tile
    const int wc   = (wid & 1)  << 6;     // wave col base within tile
    const int fr   = lane & 31;           // fragment row/col
    const int fk   = (lane >> 5) << 3;    // k sub-offset (0 or 8)

    f32x16 acc[2][2] = {};

#pragma unroll
    for (int kk = 0; kk < 4; ++kk) {      // K = 64 = 4 steps of 16
        const int kb = kk * 16 + fk;      // bf16 element offset in row
        bf16x8 a0 = *reinterpret_cast<const bf16x8*>(&As[(wr      + fr) * LDSTRIDE + kb]);
        bf16x8 a1 = *reinterpret_cast<const bf16x8*>(&As[(wr + 32 + fr) * LDSTRIDE + kb]);
        bf16x8 b0 = *reinterpret_cast<const bf16x8*>(&Bs[(wc      + fr) * LDSTRIDE + kb]);
        bf16x8 b1 = *reinterpret_cast<const bf16x8*>(&Bs[(wc + 32 + fr) * LDSTRIDE + kb]);
        acc[0][0] = __builtin_amdgcn_mfma_f32_32x32x16_bf16(a0, b0, acc[0][0], 0, 0, 0);
        acc[0][1] = __builtin_amdgcn_mfma_f32_32x32x16_bf16(a0, b1, acc[0][1], 0, 0, 0);
        acc[1][0] = __builtin_amdgcn_mfma_f32_32x32x16_bf16(a1, b0, acc[1][0], 0, 0, 0);
        acc[1][1] = __builtin_amdgcn_mfma_f32_32x32x16_bf16(a1, b1, acc[1][1], 0, 0, 0);
    }

    // ---- store: C/D layout col=lane&31, row=(reg&3)+8*(reg>>2)+4*(lane>>5) ----
    // Loop order m, r, n-inner: the two 128-B column segments of a given row
    // go out back-to-back so L2 merges them.
    float* Ob = out + (size_t)batch * (1024u * 1024u);
    const int srow = trow + wr + ((lane >> 5) << 2);
    const int scol = tcol + wc + (lane & 31);

#pragma unroll
    for (int m = 0; m < 2; ++m) {
#pragma unroll
        for (int r = 0; r < 16; ++r) {
            int roff = (r & 3) + ((r >> 2) << 3);
            float* po = Ob + (size_t)(srow + m * 32 + roff) * 1024 + scol;
#pragma unroll
            for (int n = 0; n < 2; ++n) {
                __builtin_nontemporal_store(acc[m][n][r], po + n * 32);
            }
        }
    }
}

extern "C" void kernel_launch(void* const* d_in, const int* in_sizes, int n_in,
                              void* d_out, int out_size, void* d_ws, size_t ws_size,
                              hipStream_t stream) {
    const float* q  = (const float*)d_in[0];
    const float* k  = (const float*)d_in[1];
    const float* ph = (const float*)d_in[2];
    const float* pw = (const float*)d_in[3];
    float* out = (float*)d_out;

    // 32 batches * 64 tiles (8x8 of 128x128) = 2048 blocks, 256 threads each
    hipLaunchKernelGGL(abs_pos_emb_gemm, dim3(2048), dim3(256), 0, stream,
                       q, k, ph, pw, out);
}

// Round 4
// 32.267 us; speedup vs baseline: 1.3347x; 1.0290x over previous
//
#include <hip/hip_runtime.h>

// Batched GEMM formulation of AbsolutePosEmb:
//   per batch b,n (32 of them):
//     C[xy][pq] = sum_d Q[xy][d] * (K[pq][d] + ph[p][d] + pw[q][d])
//   M = N = 1024 (HW), K = 64 (D). Output f32, compute bf16 MFMA (f32 accum).
//
// Write-BW-bound: 134 MB output at the measured ~6.85 TB/s pure-write ceiling
// -> ~22 us floor (incl. 17 MB cold reads).
//
// Round-3 change: 256x256 tiles (was 128x128).
//  - halves read traffic 134->67 MB (Q,K each re-read 4x instead of 8x)
//  - doubles per-row write burst: each block writes 1 KB contiguous per
//    output row (4 adjacent 128-B segments merged in L2) instead of 512 B.
//  - 512 threads / 8 waves, each wave a 64x128 sub-tile (acc = 8 x f32x16).
//  - LDS 73.7 KB -> dynamic (extern __shared__), 1 block/CU. Fill kernel
//    saturates write BW at ~3 waves/CU, so 8 waves/CU occupancy is enough.
// Kept from earlier rounds: chunked batch->XCD mapping (each XCD runs its 4
// batches sequentially; working set 512 KB << 4 MB L2), nontemporal stores,
// LDS row stride 72 (144 B) conflict-free for ds_read_b128.

typedef __bf16 bf16x8 __attribute__((ext_vector_type(8)));
typedef __bf16 bf16x4 __attribute__((ext_vector_type(4)));
typedef float  f32x16 __attribute__((ext_vector_type(16)));

#define LDSTRIDE 72   // bf16 elements per LDS row (64 data + 8 pad)

__global__ __launch_bounds__(512)
void abs_pos_emb_gemm(const float* __restrict__ q,
                      const float* __restrict__ k,
                      const float* __restrict__ ph,
                      const float* __restrict__ pw,
                      float* __restrict__ out)
{
    extern __shared__ __bf16 lds[];
    __bf16* As = lds;                    // Q tile   (256 rows x 64 d)
    __bf16* Bs = lds + 256 * LDSTRIDE;   // K+emb tile (256 rows x 64 d)

    const int tid = threadIdx.x;
    const int bid = blockIdx.x;
    // chunked XCD mapping over 512 blocks: XCD x = bid&7 runs batches
    // 4x..4x+3 sequentially, 16 tiles each.
    const int batch = ((bid & 7) << 2) + (bid >> 7);
    const int tile  = (bid >> 3) & 15;     // 4x4 tiles of 256x256, row-major
    const int trow  = (tile >> 2) << 8;    // tile row base in [0,1024)
    const int tcol  = (tile & 3)  << 8;    // tile col base (pq)

    const float* Qb = q + (size_t)batch * (1024 * 64);
    const float* Kb = k + (size_t)batch * (1024 * 64);

    // ---- stage A: Q tile -> bf16 LDS (coalesced float4 loads) ----
#pragma unroll
    for (int i = 0; i < 8; ++i) {
        int f   = i * 512 + tid;          // float4 index within 256x64 tile
        int row = f >> 4;                 // 16 float4 per row
        int col = (f & 15) << 2;
        float4 v = *reinterpret_cast<const float4*>(
            Qb + (size_t)(trow + row) * 64 + col);
        bf16x4 h;
        h[0] = (__bf16)v.x; h[1] = (__bf16)v.y;
        h[2] = (__bf16)v.z; h[3] = (__bf16)v.w;
        *reinterpret_cast<bf16x4*>(&As[row * LDSTRIDE + col]) = h;
    }

    // ---- stage B: (K + ph[p] + pw[q]) tile -> bf16 LDS ----
#pragma unroll
    for (int i = 0; i < 8; ++i) {
        int f   = i * 512 + tid;
        int row = f >> 4;
        int col = (f & 15) << 2;
        int grow = tcol + row;            // pq row index in [0,1024)
        int p  = grow >> 5;               // H index
        int qq = grow & 31;               // W index
        float4 v  = *reinterpret_cast<const float4*>(
            Kb + (size_t)grow * 64 + col);
        float4 vp = *reinterpret_cast<const float4*>(ph + p  * 64 + col);
        float4 vw = *reinterpret_cast<const float4*>(pw + qq * 64 + col);
        bf16x4 h;
        h[0] = (__bf16)(v.x + vp.x + vw.x);
        h[1] = (__bf16)(v.y + vp.y + vw.y);
        h[2] = (__bf16)(v.z + vp.z + vw.z);
        h[3] = (__bf16)(v.w + vp.w + vw.w);
        *reinterpret_cast<bf16x4*>(&Bs[row * LDSTRIDE + col]) = h;
    }

    __syncthreads();

    // ---- MFMA compute: 8 waves in a 4x2 grid; each wave 64x128 out ----
    const int lane = tid & 63;
    const int wid  = tid >> 6;
    const int wr   = (wid >> 1) << 6;     // wave row base: 0,64,128,192
    const int wc   = (wid & 1)  << 7;     // wave col base: 0,128
    const int fr   = lane & 31;           // fragment row/col
    const int fk   = (lane >> 5) << 3;    // k sub-offset (0 or 8)

    f32x16 acc[2][4] = {};

#pragma unroll
    for (int kk = 0; kk < 4; ++kk) {      // K = 64 = 4 steps of 16
        const int kb = kk * 16 + fk;      // bf16 element offset in row
        bf16x8 a0 = *reinterpret_cast<const bf16x8*>(&As[(wr      + fr) * LDSTRIDE + kb]);
        bf16x8 a1 = *reinterpret_cast<const bf16x8*>(&As[(wr + 32 + fr) * LDSTRIDE + kb]);
        bf16x8 b0 = *reinterpret_cast<const bf16x8*>(&Bs[(wc       + fr) * LDSTRIDE + kb]);
        bf16x8 b1 = *reinterpret_cast<const bf16x8*>(&Bs[(wc +  32 + fr) * LDSTRIDE + kb]);
        bf16x8 b2 = *reinterpret_cast<const bf16x8*>(&Bs[(wc +  64 + fr) * LDSTRIDE + kb]);
        bf16x8 b3 = *reinterpret_cast<const bf16x8*>(&Bs[(wc +  96 + fr) * LDSTRIDE + kb]);
        acc[0][0] = __builtin_amdgcn_mfma_f32_32x32x16_bf16(a0, b0, acc[0][0], 0, 0, 0);
        acc[0][1] = __builtin_amdgcn_mfma_f32_32x32x16_bf16(a0, b1, acc[0][1], 0, 0, 0);
        acc[0][2] = __builtin_amdgcn_mfma_f32_32x32x16_bf16(a0, b2, acc[0][2], 0, 0, 0);
        acc[0][3] = __builtin_amdgcn_mfma_f32_32x32x16_bf16(a0, b3, acc[0][3], 0, 0, 0);
        acc[1][0] = __builtin_amdgcn_mfma_f32_32x32x16_bf16(a1, b0, acc[1][0], 0, 0, 0);
        acc[1][1] = __builtin_amdgcn_mfma_f32_32x32x16_bf16(a1, b1, acc[1][1], 0, 0, 0);
        acc[1][2] = __builtin_amdgcn_mfma_f32_32x32x16_bf16(a1, b2, acc[1][2], 0, 0, 0);
        acc[1][3] = __builtin_amdgcn_mfma_f32_32x32x16_bf16(a1, b3, acc[1][3], 0, 0, 0);
    }

    // ---- store: C/D layout col=lane&31, row=(reg&3)+8*(reg>>2)+4*(lane>>5) ----
    // Loop order m, r, n-inner: the four adjacent 128-B column segments of a
    // given row go out back-to-back so L2 merges them into 512-B bursts
    // (1 KB per row per block together with the other column wave).
    float* Ob = out + (size_t)batch * (1024u * 1024u);
    const int srow = trow + wr + ((lane >> 5) << 2);
    const int scol = tcol + wc + (lane & 31);

#pragma unroll
    for (int m = 0; m < 2; ++m) {
#pragma unroll
        for (int r = 0; r < 16; ++r) {
            int roff = (r & 3) + ((r >> 2) << 3);
            float* po = Ob + (size_t)(srow + m * 32 + roff) * 1024 + scol;
#pragma unroll
            for (int n = 0; n < 4; ++n) {
                __builtin_nontemporal_store(acc[m][n][r], po + n * 32);
            }
        }
    }
}

extern "C" void kernel_launch(void* const* d_in, const int* in_sizes, int n_in,
                              void* d_out, int out_size, void* d_ws, size_t ws_size,
                              hipStream_t stream) {
    const float* q  = (const float*)d_in[0];
    const float* k  = (const float*)d_in[1];
    const float* ph = (const float*)d_in[2];
    const float* pw = (const float*)d_in[3];
    float* out = (float*)d_out;

    // 32 batches * 16 tiles (4x4 of 256x256) = 512 blocks, 512 threads each
    // dynamic LDS: 2 tiles * 256 rows * 72 bf16 = 73728 B
    size_t lds_bytes = 2u * 256u * LDSTRIDE * sizeof(__bf16);
    hipLaunchKernelGGL(abs_pos_emb_gemm, dim3(512), dim3(512), lds_bytes, stream,
                       q, k, ph, pw, out);
}

// Round 5
// 30.950 us; speedup vs baseline: 1.3915x; 1.0425x over previous
//
#include <hip/hip_runtime.h>

// Batched GEMM formulation of AbsolutePosEmb:
//   per batch b,n (32 of them):
//     C[xy][pq] = sum_d Q[xy][d] * (K[pq][d] + ph[p][d] + pw[q][d])
//   M = N = 1024 (HW), K = 64 (D). Output f32, compute bf16 MFMA (f32 accum).
//
// Write-BW-bound: 134 MB output; measured pure-write ceiling ~6.87 TB/s
// (harness fill kernels), mixed-copy ceiling ~6.3 TB/s -> ~22-24 us floor.
//
// Round-4 change (single A/B): REMOVE nontemporal store hint. Both calibrated
// write-BW references (fill 6.87 TB/s, float4 copy 6.3 TB/s) use plain stores
// -- L2 acts as a write-combining buffer smoothing bursts into the HBM
// controllers; nt bypass/evict-first defeats that. Read-protection rationale
// for nt is moot (hot set is 512 KB/XCD under the chunked mapping).
//
// Kept: 256x256 tiles, 512 threads / 8 waves (each 64x128 out via
// mfma_f32_32x32x16_bf16), chunked batch->XCD mapping (each XCD runs its 4
// batches sequentially, working set << 4 MB L2), LDS row stride 72 (144 B),
// store loop ordered so the 4 adjacent 128-B segments of a row go out
// back-to-back.

typedef __bf16 bf16x8 __attribute__((ext_vector_type(8)));
typedef __bf16 bf16x4 __attribute__((ext_vector_type(4)));
typedef float  f32x16 __attribute__((ext_vector_type(16)));

#define LDSTRIDE 72   // bf16 elements per LDS row (64 data + 8 pad)

__global__ __launch_bounds__(512)
void abs_pos_emb_gemm(const float* __restrict__ q,
                      const float* __restrict__ k,
                      const float* __restrict__ ph,
                      const float* __restrict__ pw,
                      float* __restrict__ out)
{
    extern __shared__ __bf16 lds[];
    __bf16* As = lds;                    // Q tile   (256 rows x 64 d)
    __bf16* Bs = lds + 256 * LDSTRIDE;   // K+emb tile (256 rows x 64 d)

    const int tid = threadIdx.x;
    const int bid = blockIdx.x;
    // chunked XCD mapping over 512 blocks: XCD x = bid&7 runs batches
    // 4x..4x+3 sequentially, 16 tiles each.
    const int batch = ((bid & 7) << 2) + (bid >> 7);
    const int tile  = (bid >> 3) & 15;     // 4x4 tiles of 256x256, row-major
    const int trow  = (tile >> 2) << 8;    // tile row base in [0,1024)
    const int tcol  = (tile & 3)  << 8;    // tile col base (pq)

    const float* Qb = q + (size_t)batch * (1024 * 64);
    const float* Kb = k + (size_t)batch * (1024 * 64);

    // ---- stage A: Q tile -> bf16 LDS (coalesced float4 loads) ----
#pragma unroll
    for (int i = 0; i < 8; ++i) {
        int f   = i * 512 + tid;          // float4 index within 256x64 tile
        int row = f >> 4;                 // 16 float4 per row
        int col = (f & 15) << 2;
        float4 v = *reinterpret_cast<const float4*>(
            Qb + (size_t)(trow + row) * 64 + col);
        bf16x4 h;
        h[0] = (__bf16)v.x; h[1] = (__bf16)v.y;
        h[2] = (__bf16)v.z; h[3] = (__bf16)v.w;
        *reinterpret_cast<bf16x4*>(&As[row * LDSTRIDE + col]) = h;
    }

    // ---- stage B: (K + ph[p] + pw[q]) tile -> bf16 LDS ----
#pragma unroll
    for (int i = 0; i < 8; ++i) {
        int f   = i * 512 + tid;
        int row = f >> 4;
        int col = (f & 15) << 2;
        int grow = tcol + row;            // pq row index in [0,1024)
        int p  = grow >> 5;               // H index
        int qq = grow & 31;               // W index
        float4 v  = *reinterpret_cast<const float4*>(
            Kb + (size_t)grow * 64 + col);
        float4 vp = *reinterpret_cast<const float4*>(ph + p  * 64 + col);
        float4 vw = *reinterpret_cast<const float4*>(pw + qq * 64 + col);
        bf16x4 h;
        h[0] = (__bf16)(v.x + vp.x + vw.x);
        h[1] = (__bf16)(v.y + vp.y + vw.y);
        h[2] = (__bf16)(v.z + vp.z + vw.z);
        h[3] = (__bf16)(v.w + vp.w + vw.w);
        *reinterpret_cast<bf16x4*>(&Bs[row * LDSTRIDE + col]) = h;
    }

    __syncthreads();

    // ---- MFMA compute: 8 waves in a 4x2 grid; each wave 64x128 out ----
    const int lane = tid & 63;
    const int wid  = tid >> 6;
    const int wr   = (wid >> 1) << 6;     // wave row base: 0,64,128,192
    const int wc   = (wid & 1)  << 7;     // wave col base: 0,128
    const int fr   = lane & 31;           // fragment row/col
    const int fk   = (lane >> 5) << 3;    // k sub-offset (0 or 8)

    f32x16 acc[2][4] = {};

#pragma unroll
    for (int kk = 0; kk < 4; ++kk) {      // K = 64 = 4 steps of 16
        const int kb = kk * 16 + fk;      // bf16 element offset in row
        bf16x8 a0 = *reinterpret_cast<const bf16x8*>(&As[(wr      + fr) * LDSTRIDE + kb]);
        bf16x8 a1 = *reinterpret_cast<const bf16x8*>(&As[(wr + 32 + fr) * LDSTRIDE + kb]);
        bf16x8 b0 = *reinterpret_cast<const bf16x8*>(&Bs[(wc       + fr) * LDSTRIDE + kb]);
        bf16x8 b1 = *reinterpret_cast<const bf16x8*>(&Bs[(wc +  32 + fr) * LDSTRIDE + kb]);
        bf16x8 b2 = *reinterpret_cast<const bf16x8*>(&Bs[(wc +  64 + fr) * LDSTRIDE + kb]);
        bf16x8 b3 = *reinterpret_cast<const bf16x8*>(&Bs[(wc +  96 + fr) * LDSTRIDE + kb]);
        acc[0][0] = __builtin_amdgcn_mfma_f32_32x32x16_bf16(a0, b0, acc[0][0], 0, 0, 0);
        acc[0][1] = __builtin_amdgcn_mfma_f32_32x32x16_bf16(a0, b1, acc[0][1], 0, 0, 0);
        acc[0][2] = __builtin_amdgcn_mfma_f32_32x32x16_bf16(a0, b2, acc[0][2], 0, 0, 0);
        acc[0][3] = __builtin_amdgcn_mfma_f32_32x32x16_bf16(a0, b3, acc[0][3], 0, 0, 0);
        acc[1][0] = __builtin_amdgcn_mfma_f32_32x32x16_bf16(a1, b0, acc[1][0], 0, 0, 0);
        acc[1][1] = __builtin_amdgcn_mfma_f32_32x32x16_bf16(a1, b1, acc[1][1], 0, 0, 0);
        acc[1][2] = __builtin_amdgcn_mfma_f32_32x32x16_bf16(a1, b2, acc[1][2], 0, 0, 0);
        acc[1][3] = __builtin_amdgcn_mfma_f32_32x32x16_bf16(a1, b3, acc[1][3], 0, 0, 0);
    }

    // ---- store: C/D layout col=lane&31, row=(reg&3)+8*(reg>>2)+4*(lane>>5) ----
    // Plain (cached) stores: let L2 write-combine the wave-granular 128-B
    // segments into smooth HBM bursts (round-4 A/B vs nontemporal).
    float* Ob = out + (size_t)batch * (1024u * 1024u);
    const int srow = trow + wr + ((lane >> 5) << 2);
    const int scol = tcol + wc + (lane & 31);

#pragma unroll
    for (int m = 0; m < 2; ++m) {
#pragma unroll
        for (int r = 0; r < 16; ++r) {
            int roff = (r & 3) + ((r >> 2) << 3);
            float* po = Ob + (size_t)(srow + m * 32 + roff) * 1024 + scol;
#pragma unroll
            for (int n = 0; n < 4; ++n) {
                po[n * 32] = acc[m][n][r];
            }
        }
    }
}

extern "C" void kernel_launch(void* const* d_in, const int* in_sizes, int n_in,
                              void* d_out, int out_size, void* d_ws, size_t ws_size,
                              hipStream_t stream) {
    const float* q  = (const float*)d_in[0];
    const float* k  = (const float*)d_in[1];
    const float* ph = (const float*)d_in[2];
    const float* pw = (const float*)d_in[3];
    float* out = (float*)d_out;

    // 32 batches * 16 tiles (4x4 of 256x256) = 512 blocks, 512 threads each
    // dynamic LDS: 2 tiles * 256 rows * 72 bf16 = 73728 B
    size_t lds_bytes = 2u * 256u * LDSTRIDE * sizeof(__bf16);
    hipLaunchKernelGGL(abs_pos_emb_gemm, dim3(512), dim3(512), lds_bytes, stream,
                       q, k, ph, pw, out);
}

// Round 6
// 29.938 us; speedup vs baseline: 1.4386x; 1.0338x over previous
//
#include <hip/hip_runtime.h>

// Batched GEMM formulation of AbsolutePosEmb:
//   per batch b,n (32 of them):
//     C[xy][pq] = sum_d Q[xy][d] * (K[pq][d] + ph[p][d] + pw[q][d])
//   M = N = 1024 (HW), K = 64 (D). Output f32, compute bf16 MFMA (f32 accum).
//
// Write-BW-bound: 134 MB output; measured pure-write ceiling ~6.87 TB/s.
//
// Round-6 change: TWO-TILE SOFTWARE PIPELINE per block (grid 256 = 1/CU).
// Previous rounds showed per-byte efficiency tweaks move ~1 us each; the
// remaining gap is bulk-synchronous phase alignment (all blocks stage, then
// all compute, then all store -> store pipe idle during staging). Each block
// now does two column-adjacent tiles of one row band:
//   stage A+B0 | bar | MFMA0 | issue K1 loads | store C0 (loads in flight)
//   | convert+ds_write B1 | bar | MFMA1 | store C1
// - A (Q) staged once for both tiles -> Q traffic halved (loads 67->48 MB)
// - tile-1 K global loads hide under tile-0's 128 stores (T14-style split)
// - LDS = A + B0 + B1 = 110.6 KB dynamic (<=160 KB; >64 KB proven round 3)
// Kept: chunked batch->XCD mapping, plain (cached) stores, LDSTRIDE=72.

typedef __bf16 bf16x8 __attribute__((ext_vector_type(8)));
typedef __bf16 bf16x4 __attribute__((ext_vector_type(4)));
typedef float  f32x16 __attribute__((ext_vector_type(16)));

#define LDSTRIDE 72   // bf16 elements per LDS row (64 data + 8 pad)

__global__ __launch_bounds__(512)
void abs_pos_emb_gemm(const float* __restrict__ q,
                      const float* __restrict__ k,
                      const float* __restrict__ ph,
                      const float* __restrict__ pw,
                      float* __restrict__ out)
{
    extern __shared__ __bf16 lds[];
    __bf16* As  = lds;                     // Q tile   (256 rows x 64 d)
    __bf16* Bs0 = lds + 256 * LDSTRIDE;    // K+emb tile 0
    __bf16* Bs1 = lds + 512 * LDSTRIDE;    // K+emb tile 1

    const int tid = threadIdx.x;
    const int bid = blockIdx.x;            // [0,256)
    // chunked XCD mapping: XCD x = bid&7 runs batches 4x..4x+3 sequentially,
    // 8 blocks (= 8 tile-pairs) per batch.
    const int batch = ((bid & 7) << 2) + (bid >> 6);
    const int j     = (bid >> 3) & 7;      // tile-pair index in batch
    const int trow  = (j >> 1) << 8;       // row band: 0,256,512,768
    const int tcol0 = (j & 1) << 9;        // 0 or 512
    const int tcol1 = tcol0 + 256;

    const float* Qb = q + (size_t)batch * (1024 * 64);
    const float* Kb = k + (size_t)batch * (1024 * 64);
    float* Ob = out + (size_t)batch * (1024u * 1024u);

    // ---- stage A: Q tile -> bf16 LDS (coalesced float4 loads) ----
#pragma unroll
    for (int i = 0; i < 8; ++i) {
        int f   = i * 512 + tid;          // float4 index within 256x64 tile
        int row = f >> 4;                 // 16 float4 per row
        int col = (f & 15) << 2;
        float4 v = *reinterpret_cast<const float4*>(
            Qb + (size_t)(trow + row) * 64 + col);
        bf16x4 h;
        h[0] = (__bf16)v.x; h[1] = (__bf16)v.y;
        h[2] = (__bf16)v.z; h[3] = (__bf16)v.w;
        *reinterpret_cast<bf16x4*>(&As[row * LDSTRIDE + col]) = h;
    }

    // ---- stage B0: (K + ph[p] + pw[q]) tile 0 -> bf16 LDS ----
#pragma unroll
    for (int i = 0; i < 8; ++i) {
        int f   = i * 512 + tid;
        int row = f >> 4;
        int col = (f & 15) << 2;
        int grow = tcol0 + row;           // pq row index
        int p  = grow >> 5;               // H index
        int qq = grow & 31;               // W index
        float4 v  = *reinterpret_cast<const float4*>(
            Kb + (size_t)grow * 64 + col);
        float4 vp = *reinterpret_cast<const float4*>(ph + p  * 64 + col);
        float4 vw = *reinterpret_cast<const float4*>(pw + qq * 64 + col);
        bf16x4 h;
        h[0] = (__bf16)(v.x + vp.x + vw.x);
        h[1] = (__bf16)(v.y + vp.y + vw.y);
        h[2] = (__bf16)(v.z + vp.z + vw.z);
        h[3] = (__bf16)(v.w + vp.w + vw.w);
        *reinterpret_cast<bf16x4*>(&Bs0[row * LDSTRIDE + col]) = h;
    }

    __syncthreads();

    // ---- wave geometry: 8 waves in a 4x2 grid; each wave 64x128 out ----
    const int lane = tid & 63;
    const int wid  = tid >> 6;
    const int wr   = (wid >> 1) << 6;     // wave row base: 0,64,128,192
    const int wc   = (wid & 1)  << 7;     // wave col base: 0,128
    const int fr   = lane & 31;           // fragment row/col
    const int fk   = (lane >> 5) << 3;    // k sub-offset (0 or 8)

    f32x16 acc[2][4];
#pragma unroll
    for (int m = 0; m < 2; ++m)
#pragma unroll
        for (int n2 = 0; n2 < 4; ++n2)
#pragma unroll
            for (int e = 0; e < 16; ++e) acc[m][n2][e] = 0.0f;

    // ---- MFMA tile 0 ----
#pragma unroll
    for (int kk = 0; kk < 4; ++kk) {      // K = 64 = 4 steps of 16
        const int kb = kk * 16 + fk;
        bf16x8 a0 = *reinterpret_cast<const bf16x8*>(&As[(wr      + fr) * LDSTRIDE + kb]);
        bf16x8 a1 = *reinterpret_cast<const bf16x8*>(&As[(wr + 32 + fr) * LDSTRIDE + kb]);
        bf16x8 b0 = *reinterpret_cast<const bf16x8*>(&Bs0[(wc      + fr) * LDSTRIDE + kb]);
        bf16x8 b1 = *reinterpret_cast<const bf16x8*>(&Bs0[(wc + 32 + fr) * LDSTRIDE + kb]);
        bf16x8 b2 = *reinterpret_cast<const bf16x8*>(&Bs0[(wc + 64 + fr) * LDSTRIDE + kb]);
        bf16x8 b3 = *reinterpret_cast<const bf16x8*>(&Bs0[(wc + 96 + fr) * LDSTRIDE + kb]);
        acc[0][0] = __builtin_amdgcn_mfma_f32_32x32x16_bf16(a0, b0, acc[0][0], 0, 0, 0);
        acc[0][1] = __builtin_amdgcn_mfma_f32_32x32x16_bf16(a0, b1, acc[0][1], 0, 0, 0);
        acc[0][2] = __builtin_amdgcn_mfma_f32_32x32x16_bf16(a0, b2, acc[0][2], 0, 0, 0);
        acc[0][3] = __builtin_amdgcn_mfma_f32_32x32x16_bf16(a0, b3, acc[0][3], 0, 0, 0);
        acc[1][0] = __builtin_amdgcn_mfma_f32_32x32x16_bf16(a1, b0, acc[1][0], 0, 0, 0);
        acc[1][1] = __builtin_amdgcn_mfma_f32_32x32x16_bf16(a1, b1, acc[1][1], 0, 0, 0);
        acc[1][2] = __builtin_amdgcn_mfma_f32_32x32x16_bf16(a1, b2, acc[1][2], 0, 0, 0);
        acc[1][3] = __builtin_amdgcn_mfma_f32_32x32x16_bf16(a1, b3, acc[1][3], 0, 0, 0);
    }

    // ---- issue tile-1 K loads now; they fly while C0 stores drain ----
    float4 kv[8];
#pragma unroll
    for (int i = 0; i < 8; ++i) {
        int f   = i * 512 + tid;
        int row = f >> 4;
        int col = (f & 15) << 2;
        kv[i] = *reinterpret_cast<const float4*>(
            Kb + (size_t)(tcol1 + row) * 64 + col);
    }

    // ---- store C0 ----
    const int srow = trow + wr + ((lane >> 5) << 2);
    {
        const int scol = tcol0 + wc + (lane & 31);
#pragma unroll
        for (int m = 0; m < 2; ++m) {
#pragma unroll
            for (int r = 0; r < 16; ++r) {
                int roff = (r & 3) + ((r >> 2) << 3);
                float* po = Ob + (size_t)(srow + m * 32 + roff) * 1024 + scol;
#pragma unroll
                for (int n2 = 0; n2 < 4; ++n2) {
                    po[n2 * 32] = acc[m][n2][r];
                }
            }
        }
    }

    // ---- convert + LDS-write B1 (ph/pw are L1-hot) ----
#pragma unroll
    for (int i = 0; i < 8; ++i) {
        int f   = i * 512 + tid;
        int row = f >> 4;
        int col = (f & 15) << 2;
        int grow = tcol1 + row;
        int p  = grow >> 5;
        int qq = grow & 31;
        float4 vp = *reinterpret_cast<const float4*>(ph + p  * 64 + col);
        float4 vw = *reinterpret_cast<const float4*>(pw + qq * 64 + col);
        bf16x4 h;
        h[0] = (__bf16)(kv[i].x + vp.x + vw.x);
        h[1] = (__bf16)(kv[i].y + vp.y + vw.y);
        h[2] = (__bf16)(kv[i].z + vp.z + vw.z);
        h[3] = (__bf16)(kv[i].w + vp.w + vw.w);
        *reinterpret_cast<bf16x4*>(&Bs1[row * LDSTRIDE + col]) = h;
    }

    __syncthreads();

    // ---- MFMA tile 1 ----
#pragma unroll
    for (int m = 0; m < 2; ++m)
#pragma unroll
        for (int n2 = 0; n2 < 4; ++n2)
#pragma unroll
            for (int e = 0; e < 16; ++e) acc[m][n2][e] = 0.0f;

#pragma unroll
    for (int kk = 0; kk < 4; ++kk) {
        const int kb = kk * 16 + fk;
        bf16x8 a0 = *reinterpret_cast<const bf16x8*>(&As[(wr      + fr) * LDSTRIDE + kb]);
        bf16x8 a1 = *reinterpret_cast<const bf16x8*>(&As[(wr + 32 + fr) * LDSTRIDE + kb]);
        bf16x8 b0 = *reinterpret_cast<const bf16x8*>(&Bs1[(wc      + fr) * LDSTRIDE + kb]);
        bf16x8 b1 = *reinterpret_cast<const bf16x8*>(&Bs1[(wc + 32 + fr) * LDSTRIDE + kb]);
        bf16x8 b2 = *reinterpret_cast<const bf16x8*>(&Bs1[(wc + 64 + fr) * LDSTRIDE + kb]);
        bf16x8 b3 = *reinterpret_cast<const bf16x8*>(&Bs1[(wc + 96 + fr) * LDSTRIDE + kb]);
        acc[0][0] = __builtin_amdgcn_mfma_f32_32x32x16_bf16(a0, b0, acc[0][0], 0, 0, 0);
        acc[0][1] = __builtin_amdgcn_mfma_f32_32x32x16_bf16(a0, b1, acc[0][1], 0, 0, 0);
        acc[0][2] = __builtin_amdgcn_mfma_f32_32x32x16_bf16(a0, b2, acc[0][2], 0, 0, 0);
        acc[0][3] = __builtin_amdgcn_mfma_f32_32x32x16_bf16(a0, b3, acc[0][3], 0, 0, 0);
        acc[1][0] = __builtin_amdgcn_mfma_f32_32x32x16_bf16(a1, b0, acc[1][0], 0, 0, 0);
        acc[1][1] = __builtin_amdgcn_mfma_f32_32x32x16_bf16(a1, b1, acc[1][1], 0, 0, 0);
        acc[1][2] = __builtin_amdgcn_mfma_f32_32x32x16_bf16(a1, b2, acc[1][2], 0, 0, 0);
        acc[1][3] = __builtin_amdgcn_mfma_f32_32x32x16_bf16(a1, b3, acc[1][3], 0, 0, 0);
    }

    // ---- store C1 ----
    {
        const int scol = tcol1 + wc + (lane & 31);
#pragma unroll
        for (int m = 0; m < 2; ++m) {
#pragma unroll
            for (int r = 0; r < 16; ++r) {
                int roff = (r & 3) + ((r >> 2) << 3);
                float* po = Ob + (size_t)(srow + m * 32 + roff) * 1024 + scol;
#pragma unroll
                for (int n2 = 0; n2 < 4; ++n2) {
                    po[n2 * 32] = acc[m][n2][r];
                }
            }
        }
    }
}

extern "C" void kernel_launch(void* const* d_in, const int* in_sizes, int n_in,
                              void* d_out, int out_size, void* d_ws, size_t ws_size,
                              hipStream_t stream) {
    const float* q  = (const float*)d_in[0];
    const float* k  = (const float*)d_in[1];
    const float* ph = (const float*)d_in[2];
    const float* pw = (const float*)d_in[3];
    float* out = (float*)d_out;

    // 32 batches * 8 tile-pairs = 256 blocks (1/CU), 512 threads each.
    // dynamic LDS: 3 buffers * 256 rows * 72 bf16 * 2 B = 110592 B
    size_t lds_bytes = 3u * 256u * LDSTRIDE * sizeof(__bf16);
    hipLaunchKernelGGL(abs_pos_emb_gemm, dim3(256), dim3(512), lds_bytes, stream,
                       q, k, ph, pw, out);
}

// Round 7
// 28.723 us; speedup vs baseline: 1.4994x; 1.0423x over previous
//
#include <hip/hip_runtime.h>

// Batched GEMM formulation of AbsolutePosEmb:
//   per batch b,n (32 of them):
//     C[xy][pq] = sum_d Q[xy][d] * (K[pq][d] + ph[p][d] + pw[q][d])
//   M = N = 1024 (HW), K = 64 (D). Output f32, compute bf16 MFMA (f32 accum).
//
// Write-BW-bound: 134 MB output; pure-write ceiling ~6.87 TB/s -> ~22-23 us
// floor incl. 17 MB cold reads.
//
// Round-7: FINE-GRAINED CHUNK PIPELINE. Each block owns one 256x512 output
// strip (rows trow..trow+255, cols tcol0..tcol0+511) of one batch; the
// B-operand (K+emb) is staged in EIGHT 64-row chunks (16 KB each), double
// buffered, instead of two 256-row tiles. Per chunk:
//   prefetch chunk c+1 (6 float4 -> regs, issued BEFORE the stores so the
//   convert waits at vmcnt(32) without draining the store queue)
//   -> 8 MFMA -> 32 stores (fire-and-forget) -> convert+ds_write -> barrier.
// First stores issue after only 80 KB staged per block (vs 128 KB), and
// staging stays interleaved at 16 KB granularity -> the store stream starts
// ~1.5-2 us earlier and never starves mid-kernel.
// Kept: chunked batch->XCD mapping, plain cached stores, LDSTRIDE=72,
// A (Q) staged once per block and reused by all 8 chunks.

typedef __bf16 bf16x8 __attribute__((ext_vector_type(8)));
typedef __bf16 bf16x4 __attribute__((ext_vector_type(4)));
typedef float  f32x16 __attribute__((ext_vector_type(16)));

#define LDSTRIDE 72   // bf16 elements per LDS row (64 data + 8 pad)

__global__ __launch_bounds__(512)
void abs_pos_emb_gemm(const float* __restrict__ q,
                      const float* __restrict__ k,
                      const float* __restrict__ ph,
                      const float* __restrict__ pw,
                      float* __restrict__ out)
{
    extern __shared__ __bf16 lds[];
    __bf16* As  = lds;                     // Q tile: 256 rows x 64 d
    __bf16* Bs0 = lds + 256 * LDSTRIDE;    // B chunk buffer 0: 64 x 64
    __bf16* Bs1 = lds + 320 * LDSTRIDE;    // B chunk buffer 1: 64 x 64

    const int tid = threadIdx.x;
    const int bid = blockIdx.x;            // [0,256)
    // chunked XCD mapping: XCD x = bid&7 runs batches 4x..4x+3 sequentially.
    const int batch = ((bid & 7) << 2) + (bid >> 6);
    const int j     = (bid >> 3) & 7;      // strip index in batch
    const int trow  = (j >> 1) << 8;       // row band: 0,256,512,768
    const int tcol0 = (j & 1) << 9;        // col half: 0 or 512 (strip = 512 wide)

    const float* Qb = q + (size_t)batch * (1024 * 64);
    const float* Kb = k + (size_t)batch * (1024 * 64);
    float* Ob = out + (size_t)batch * (1024u * 1024u);

    // ---- stage A: Q tile (256x64) -> bf16 LDS ----
#pragma unroll
    for (int i = 0; i < 8; ++i) {
        int f   = i * 512 + tid;
        int row = f >> 4;
        int col = (f & 15) << 2;
        float4 v = *reinterpret_cast<const float4*>(
            Qb + (size_t)(trow + row) * 64 + col);
        bf16x4 h;
        h[0] = (__bf16)v.x; h[1] = (__bf16)v.y;
        h[2] = (__bf16)v.z; h[3] = (__bf16)v.w;
        *reinterpret_cast<bf16x4*>(&As[row * LDSTRIDE + col]) = h;
    }

    // ---- stage B chunk 0 (64 rows) ----
#pragma unroll
    for (int i = 0; i < 2; ++i) {
        int f   = i * 512 + tid;
        int row = f >> 4;                 // 0..63
        int col = (f & 15) << 2;
        int grow = tcol0 + row;
        int p  = grow >> 5;
        int qq = grow & 31;
        float4 v  = *reinterpret_cast<const float4*>(Kb + (size_t)grow * 64 + col);
        float4 vp = *reinterpret_cast<const float4*>(ph + p  * 64 + col);
        float4 vw = *reinterpret_cast<const float4*>(pw + qq * 64 + col);
        bf16x4 h;
        h[0] = (__bf16)(v.x + vp.x + vw.x);
        h[1] = (__bf16)(v.y + vp.y + vw.y);
        h[2] = (__bf16)(v.z + vp.z + vw.z);
        h[3] = (__bf16)(v.w + vp.w + vw.w);
        *reinterpret_cast<bf16x4*>(&Bs0[row * LDSTRIDE + col]) = h;
    }

    __syncthreads();

    // ---- wave geometry: 8 waves, 4x2 grid; per chunk each wave does 64x32 ----
    const int lane = tid & 63;
    const int wid  = tid >> 6;
    const int wrow = (wid >> 1) << 6;     // 0,64,128,192
    const int wcl  = (wid & 1)  << 5;     // 0,32 (within 64-col chunk)
    const int fr   = lane & 31;
    const int fk   = (lane >> 5) << 3;
    const int srow = trow + wrow + ((lane >> 5) << 2);

    // prefetch staging coordinates (fixed per thread)
    const int prow0 = tid >> 4;           // 0..31
    const int prow1 = prow0 + 32;         // 32..63
    const int pcol  = (tid & 15) << 2;

#pragma unroll
    for (int c = 0; c < 8; ++c) {
        const __bf16* B  = (c & 1) ? Bs1 : Bs0;
        __bf16*       Bn = (c & 1) ? Bs0 : Bs1;

        // ---- prefetch chunk c+1 into regs (before stores -> no queue drain)
        float4 kv0, kv1, vp0, vp1, vw0, vw1;
        if (c < 7) {
            int g0 = tcol0 + (c + 1) * 64 + prow0;
            int g1 = tcol0 + (c + 1) * 64 + prow1;
            kv0 = *reinterpret_cast<const float4*>(Kb + (size_t)g0 * 64 + pcol);
            kv1 = *reinterpret_cast<const float4*>(Kb + (size_t)g1 * 64 + pcol);
            vp0 = *reinterpret_cast<const float4*>(ph + (g0 >> 5) * 64 + pcol);
            vp1 = *reinterpret_cast<const float4*>(ph + (g1 >> 5) * 64 + pcol);
            vw0 = *reinterpret_cast<const float4*>(pw + (g0 & 31) * 64 + pcol);
            vw1 = *reinterpret_cast<const float4*>(pw + (g1 & 31) * 64 + pcol);
        }

        // ---- MFMA chunk c ----
        f32x16 acc0 = {};
        f32x16 acc1 = {};
#pragma unroll
        for (int kk = 0; kk < 4; ++kk) {
            const int kb = kk * 16 + fk;
            bf16x8 a0 = *reinterpret_cast<const bf16x8*>(&As[(wrow      + fr) * LDSTRIDE + kb]);
            bf16x8 a1 = *reinterpret_cast<const bf16x8*>(&As[(wrow + 32 + fr) * LDSTRIDE + kb]);
            bf16x8 b0 = *reinterpret_cast<const bf16x8*>(&B [(wcl       + fr) * LDSTRIDE + kb]);
            acc0 = __builtin_amdgcn_mfma_f32_32x32x16_bf16(a0, b0, acc0, 0, 0, 0);
            acc1 = __builtin_amdgcn_mfma_f32_32x32x16_bf16(a1, b0, acc1, 0, 0, 0);
        }

        // ---- store chunk c output (256 x 64 cols at tcol0 + c*64) ----
        {
            const int scol = tcol0 + (c << 6) + wcl + fr;
#pragma unroll
            for (int r = 0; r < 16; ++r) {
                int roff = (r & 3) + ((r >> 2) << 3);
                Ob[(size_t)(srow + roff) * 1024 + scol]      = acc0[r];
            }
#pragma unroll
            for (int r = 0; r < 16; ++r) {
                int roff = (r & 3) + ((r >> 2) << 3);
                Ob[(size_t)(srow + 32 + roff) * 1024 + scol] = acc1[r];
            }
        }

        // ---- convert + ds_write chunk c+1, then barrier ----
        if (c < 7) {
            bf16x4 h0, h1;
            h0[0] = (__bf16)(kv0.x + vp0.x + vw0.x);
            h0[1] = (__bf16)(kv0.y + vp0.y + vw0.y);
            h0[2] = (__bf16)(kv0.z + vp0.z + vw0.z);
            h0[3] = (__bf16)(kv0.w + vp0.w + vw0.w);
            h1[0] = (__bf16)(kv1.x + vp1.x + vw1.x);
            h1[1] = (__bf16)(kv1.y + vp1.y + vw1.y);
            h1[2] = (__bf16)(kv1.z + vp1.z + vw1.z);
            h1[3] = (__bf16)(kv1.w + vp1.w + vw1.w);
            *reinterpret_cast<bf16x4*>(&Bn[prow0 * LDSTRIDE + pcol]) = h0;
            *reinterpret_cast<bf16x4*>(&Bn[prow1 * LDSTRIDE + pcol]) = h1;
            __syncthreads();
        }
    }
}

extern "C" void kernel_launch(void* const* d_in, const int* in_sizes, int n_in,
                              void* d_out, int out_size, void* d_ws, size_t ws_size,
                              hipStream_t stream) {
    const float* q  = (const float*)d_in[0];
    const float* k  = (const float*)d_in[1];
    const float* ph = (const float*)d_in[2];
    const float* pw = (const float*)d_in[3];
    float* out = (float*)d_out;

    // 32 batches * 8 strips (256 rows x 512 cols) = 256 blocks, 512 threads.
    // dynamic LDS: A 256 rows + 2 B-chunk buffers (64 rows each), stride 72:
    // (256 + 128) * 72 * 2 B = 55296 B
    size_t lds_bytes = (256u + 128u) * LDSTRIDE * sizeof(__bf16);
    hipLaunchKernelGGL(abs_pos_emb_gemm, dim3(256), dim3(512), lds_bytes, stream,
                       q, k, ph, pw, out);
}